// Round 8
// baseline (179.567 us; speedup 1.0000x reference)
//
#include <hip/hip_runtime.h>
#include <cstdint>

#define S_CNT 10000
#define R_CNT 10000
#define PG 1024            // p-groups
#define PROWS 49           // p-rows per group (1024*49 = 50176 >= 50000)
#define CAP 1216           // slots per group: E~977, sigma~31 -> +7.5 sigma (even)
#define SPLIT 2            // compute blocks per group -> grid 2048
#define PACKED_OFF_B 16384
#define WS_NEED ((size_t)PACKED_OFF_B + 8ull * PG * CAP)
#define MAXROW (S_CNT * 50 - 1)   // 499999: clamp decoded rows so garbage slots can't go OOB

__device__ __forceinline__ unsigned bfpack(float a, float b) {
    unsigned ua = __float_as_uint(a), ub = __float_as_uint(b);
    ua = (ua + 0x7FFFu + ((ua >> 16) & 1u)) >> 16;       // round-to-nearest-even bf16
    ub = (ub + 0x7FFFu + ((ub >> 16) & 1u)) >> 16;
    return ua | (ub << 16);
}
__device__ __forceinline__ float blo(unsigned u) { return __uint_as_float(u << 16); }
__device__ __forceinline__ float bhi(unsigned u) { return __uint_as_float(u & 0xFFFF0000u); }

// ---- pass 0: zero the group cursors (1024 ints) ----
__global__ __launch_bounds__(256) void zero_kernel(int4* __restrict__ cur4) {
    cur4[threadIdx.x] = make_int4(0, 0, 0, 0);
}

// ---- pass 1: single-pass bin-by-p-group scatter (block reservation) ----
// record: w0 = s | t<<14 | dp<<20 | (idx&63)<<26 ; w1 = r | (idx>>6)<<14
__global__ __launch_bounds__(256) void bin_kernel(
    const int* __restrict__ X, int n, int* __restrict__ cursors,
    int2* __restrict__ packed,
    const float* __restrict__ se, const float* __restrict__ re,
    const float* __restrict__ pe, float* __restrict__ out)
{
    __shared__ int lhist[PG], lbase[PG], lcur[PG];
    const int tid = threadIdx.x;
    const long long base = (long long)blockIdx.x * 1024;

    #pragma unroll
    for (int k = 0; k < PG / 256; ++k) lhist[tid + 256 * k] = 0;
    __syncthreads();

    int4 xs[4];
    int  grp[4];
    #pragma unroll
    for (int it = 0; it < 4; ++it) {
        const long long i = base + it * 256 + tid;
        if (i < n) {
            xs[it] = *reinterpret_cast<const int4*>(X + 4 * i);
            grp[it] = xs[it].z / PROWS;
            atomicAdd(&lhist[grp[it]], 1);
        } else grp[it] = -1;
    }
    __syncthreads();
    #pragma unroll
    for (int k = 0; k < PG / 256; ++k) {
        const int b = tid + 256 * k;
        const int c = lhist[b];
        lbase[b] = c ? atomicAdd(&cursors[b], c) : 0;
        lcur[b] = 0;
    }
    __syncthreads();
    #pragma unroll
    for (int it = 0; it < 4; ++it) {
        const int g = grp[it];
        if (g < 0) continue;
        const unsigned i = (unsigned)(base + it * 256 + tid);
        const int rank = lbase[g] + atomicAdd(&lcur[g], 1);
        if (rank < CAP) {
            const unsigned dp = (unsigned)(xs[it].z - g * PROWS);
            packed[g * CAP + rank] = make_int2(
                (int)((unsigned)xs[it].x | ((unsigned)xs[it].w << 14) | (dp << 20) | ((i & 63u) << 26)),
                (int)((unsigned)xs[it].y | ((i >> 6) << 14)));
        } else {
            // statistically unreachable overflow: compute sample directly
            const long long st = (long long)xs[it].x + (long long)xs[it].w * S_CNT;
            const long long rt = (long long)xs[it].y + (long long)xs[it].w * R_CNT;
            const long long p  = xs[it].z;
            float acc = 0.f;
            for (int k = 0; k < 64; ++k)
                acc += se[st * 64 + k] * pe[p * 128 + k]
                     + re[rt * 64 + k] * pe[p * 128 + 64 + k];
            out[i] = 1.0f / (1.0f + __expf(-acc));
        }
    }
}

// ---- pass 2: compute. p in LDS (bf16); depth-1 software-pipelined gathers ----
// Stage S: load packed pair for chunk j, decode (+clamp), issue 4 gathers.
#define PIPE_LOAD(S, jv)                                                        \
    {                                                                           \
        jA_##S = (jv);                                                          \
        const int jc = min(jA_##S, CAP - 2);                                    \
        const int4 w = *reinterpret_cast<const int4*>(pk + jc);                 \
        const unsigned a0 = (unsigned)w.x, a1 = (unsigned)w.y;                  \
        const unsigned b0 = (unsigned)w.z, b1 = (unsigned)w.w;                  \
        const int stA = min((int)(a0 & 0x3FFFu) + (int)((a0 >> 14) & 0x3Fu) * S_CNT, MAXROW); \
        const int rtA = min((int)(a1 & 0x3FFFu) + (int)((a0 >> 14) & 0x3Fu) * R_CNT, MAXROW); \
        const int stB = min((int)(b0 & 0x3FFFu) + (int)((b0 >> 14) & 0x3Fu) * S_CNT, MAXROW); \
        const int rtB = min((int)(b1 & 0x3FFFu) + (int)((b0 >> 14) & 0x3Fu) * R_CNT, MAXROW); \
        dpA_##S  = min((int)((a0 >> 20) & 0x3Fu), PROWS - 1);                   \
        idxA_##S = (int)((a0 >> 26) | ((a1 >> 14) << 6));                       \
        dpB_##S  = min((int)((b0 >> 20) & 0x3Fu), PROWS - 1);                   \
        idxB_##S = (int)((b0 >> 26) | ((b1 >> 14) << 6));                       \
        seA_##S = *reinterpret_cast<const float4*>(sbase + (unsigned)stA * 64u);\
        reA_##S = *reinterpret_cast<const float4*>(rbase + (unsigned)rtA * 64u);\
        seB_##S = *reinterpret_cast<const float4*>(sbase + (unsigned)stB * 64u);\
        reB_##S = *reinterpret_cast<const float4*>(rbase + (unsigned)rtB * 64u);\
    }

#define PIPE_COMPUTE(S)                                                         \
    {                                                                           \
        const int pbA = dpA_##S * 64;                                           \
        const int pbB = dpB_##S * 64;                                           \
        const uint2 uplA = *reinterpret_cast<const uint2*>(&plds[pbA + l * 2]); \
        const uint2 uphA = *reinterpret_cast<const uint2*>(&plds[pbA + 32 + l * 2]); \
        const uint2 uplB = *reinterpret_cast<const uint2*>(&plds[pbB + l * 2]); \
        const uint2 uphB = *reinterpret_cast<const uint2*>(&plds[pbB + 32 + l * 2]); \
        float accA = seA_##S.x * blo(uplA.x) + seA_##S.y * bhi(uplA.x)          \
                   + seA_##S.z * blo(uplA.y) + seA_##S.w * bhi(uplA.y)          \
                   + reA_##S.x * blo(uphA.x) + reA_##S.y * bhi(uphA.x)          \
                   + reA_##S.z * blo(uphA.y) + reA_##S.w * bhi(uphA.y);         \
        float accB = seB_##S.x * blo(uplB.x) + seB_##S.y * bhi(uplB.x)          \
                   + seB_##S.z * blo(uplB.y) + seB_##S.w * bhi(uplB.y)          \
                   + reB_##S.x * blo(uphB.x) + reB_##S.y * bhi(uphB.x)          \
                   + reB_##S.z * blo(uphB.y) + reB_##S.w * bhi(uphB.y);         \
        accA += __shfl_xor(accA, 1, 64);  accB += __shfl_xor(accB, 1, 64);      \
        accA += __shfl_xor(accA, 2, 64);  accB += __shfl_xor(accB, 2, 64);      \
        accA += __shfl_xor(accA, 4, 64);  accB += __shfl_xor(accB, 4, 64);      \
        accA += __shfl_xor(accA, 8, 64);  accB += __shfl_xor(accB, 8, 64);      \
        if (l == 0) {                                                           \
            if (jA_##S     <= last) out[idxA_##S] = 1.0f / (1.0f + __expf(-accA)); \
            if (jA_##S + 1 <= last) out[idxB_##S] = 1.0f / (1.0f + __expf(-accB)); \
        }                                                                       \
    }

__global__ __launch_bounds__(256, 7) void compute_kernel(
    const int* __restrict__ cursors, const int2* __restrict__ packed,
    const float* __restrict__ s_embeds, const float* __restrict__ r_embeds,
    const float* __restrict__ p_embeds, float* __restrict__ out)
{
    __shared__ __align__(16) unsigned plds[PROWS * 64];  // bf16x2, 12544 B
    const int g = blockIdx.x / SPLIT;
    const int q = blockIdx.x % SPLIT;
    const int cnt = min(cursors[g], CAP);
    if (cnt == 0) return;

    const int prow0 = g * PROWS;
    const int rows = min(PROWS, 50000 - prow0);
    const int nf4 = rows * 32;
    const float4* src = reinterpret_cast<const float4*>(p_embeds + (long long)prow0 * 128);
    for (int k = threadIdx.x; k < nf4; k += 256) {
        const float4 v = src[k];
        uint2 u;
        u.x = bfpack(v.x, v.y);
        u.y = bfpack(v.z, v.w);
        reinterpret_cast<uint2*>(plds)[k] = u;
    }
    __syncthreads();

    int mid = (cnt / 2 + 31) & ~31;
    if (mid > cnt) mid = cnt;
    const int lo  = q ? mid : 0;
    const int end = q ? cnt : mid;
    if (lo >= end) return;
    const int last = end - 1;

    const int gl = threadIdx.x >> 4;   // group 0..15
    const int l  = threadIdx.x & 15;   // lane in group
    const int2* pk = packed + g * CAP;
    const float* sbase = s_embeds + l * 4;
    const float* rbase = r_embeds + l * 4;

    // stage registers (static names; no runtime-indexed arrays -> no scratch)
    int jA_0, dpA_0, idxA_0, dpB_0, idxB_0;
    int jA_1, dpA_1, idxA_1, dpB_1, idxB_1;
    float4 seA_0, reA_0, seB_0, reB_0;
    float4 seA_1, reA_1, seB_1, reB_1;

    int j = lo + gl * 2;               // this group's first pair slot
    if (j <= last) {
        PIPE_LOAD(0, j);
        j += 32;
        while (true) {
            if (j > last) { PIPE_COMPUTE(0); break; }
            PIPE_LOAD(1, j);           // issue next-chunk gathers BEFORE waiting on current
            PIPE_COMPUTE(0);
            j += 32;
            if (j > last) { PIPE_COMPUTE(1); break; }
            PIPE_LOAD(0, j);
            PIPE_COMPUTE(1);
            j += 32;
        }
    }
}

// ---- fallback: direct kernel (only if workspace too small) ----
__global__ __launch_bounds__(256) void direct_kernel(
    const int* __restrict__ X,
    const float* __restrict__ s_embeds, const float* __restrict__ r_embeds,
    const float* __restrict__ p_embeds, float* __restrict__ out, int n) {
    const int g = threadIdx.x >> 4;
    const int l = threadIdx.x & 15;
    const int i = blockIdx.x * 16 + g;
    if (i >= n) return;
    const int4 xi = *reinterpret_cast<const int4*>(X + 4ll * i);
    const long long st = (long long)xi.x + (long long)xi.w * S_CNT;
    const long long rt = (long long)xi.y + (long long)xi.w * R_CNT;
    const long long p  = xi.z;
    const float4 se = *reinterpret_cast<const float4*>(s_embeds + st * 64 + l * 4);
    const float4 re = *reinterpret_cast<const float4*>(r_embeds + rt * 64 + l * 4);
    const float4 pl = *reinterpret_cast<const float4*>(p_embeds + p * 128 + l * 4);
    const float4 ph = *reinterpret_cast<const float4*>(p_embeds + p * 128 + 64 + l * 4);
    float acc = se.x * pl.x + se.y * pl.y + se.z * pl.z + se.w * pl.w
              + re.x * ph.x + re.y * ph.y + re.z * ph.z + re.w * ph.w;
    acc += __shfl_xor(acc, 1, 64);
    acc += __shfl_xor(acc, 2, 64);
    acc += __shfl_xor(acc, 4, 64);
    acc += __shfl_xor(acc, 8, 64);
    if (l == 0) out[i] = 1.0f / (1.0f + __expf(-acc));
}

extern "C" void kernel_launch(void* const* d_in, const int* in_sizes, int n_in,
                              void* d_out, int out_size, void* d_ws, size_t ws_size,
                              hipStream_t stream) {
    const int*   X        = (const int*)d_in[0];
    const float* s_embeds = (const float*)d_in[1];
    const float* r_embeds = (const float*)d_in[2];
    const float* p_embeds = (const float*)d_in[3];
    float* out = (float*)d_out;
    const int n = in_sizes[0] / 4;

    if (ws_size < WS_NEED) {
        direct_kernel<<<(n + 15) / 16, 256, 0, stream>>>(
            X, s_embeds, r_embeds, p_embeds, out, n);
        return;
    }

    int* cursors = (int*)d_ws;
    int2* packed = reinterpret_cast<int2*>((char*)d_ws + PACKED_OFF_B);

    zero_kernel<<<1, 256, 0, stream>>>(reinterpret_cast<int4*>(cursors));
    bin_kernel<<<(n + 1023) / 1024, 256, 0, stream>>>(
        X, n, cursors, packed, s_embeds, r_embeds, p_embeds, out);
    compute_kernel<<<PG * SPLIT, 256, 0, stream>>>(
        cursors, packed, s_embeds, r_embeds, p_embeds, out);
}

// Round 9
// 167.317 us; speedup vs baseline: 1.0732x; 1.0732x over previous
//
#include <hip/hip_runtime.h>
#include <cstdint>

#define S_CNT 10000
#define R_CNT 10000
#define PG 2000            // p-bins (25 rows each: 2000*25 = 50000 exactly)
#define PROWS 25
#define CAP 634            // E=500, sigma~22.4 -> +6 sigma, even
#define PACKED_OFF_B 16384
#define WS_NEED ((size_t)PACKED_OFF_B + 16ull * PG * CAP)   // ~20.3 MB

// ---- pass 0: zero the bin cursors (2048 ints) ----
__global__ __launch_bounds__(256) void zero_kernel(int4* __restrict__ cur4) {
    cur4[blockIdx.x * 256 + threadIdx.x] = make_int4(0, 0, 0, 0);  // grid=2
}

// ---- pass 1: single-pass bin-by-p-window scatter (block reservation) ----
// record: {st, rt, p, idx} — zero decode work in the compute kernel
__global__ __launch_bounds__(256) void bin_kernel(
    const int* __restrict__ X, int n, int* __restrict__ cursors,
    int4* __restrict__ packed,
    const float* __restrict__ se, const float* __restrict__ re,
    const float* __restrict__ pe, float* __restrict__ out)
{
    __shared__ int lhist[PG], lbase[PG], lcur[PG];
    const int tid = threadIdx.x;
    const long long base = (long long)blockIdx.x * 1024;

    for (int k = tid; k < PG; k += 256) lhist[k] = 0;
    __syncthreads();

    int4 xs[4];
    int  grp[4];
    #pragma unroll
    for (int it = 0; it < 4; ++it) {
        const long long i = base + it * 256 + tid;
        if (i < n) {
            xs[it] = *reinterpret_cast<const int4*>(X + 4 * i);
            grp[it] = xs[it].z / PROWS;
            atomicAdd(&lhist[grp[it]], 1);
        } else grp[it] = -1;
    }
    __syncthreads();
    for (int k = tid; k < PG; k += 256) {
        const int c = lhist[k];
        lbase[k] = c ? atomicAdd(&cursors[k], c) : 0;
        lcur[k] = 0;
    }
    __syncthreads();
    #pragma unroll
    for (int it = 0; it < 4; ++it) {
        const int g = grp[it];
        if (g < 0) continue;
        const int i = (int)(base + it * 256 + tid);
        const int rank = lbase[g] + atomicAdd(&lcur[g], 1);
        if (rank < CAP) {
            packed[(long long)g * CAP + rank] =
                make_int4(xs[it].x + xs[it].w * S_CNT,
                          xs[it].y + xs[it].w * R_CNT,
                          xs[it].z, i);
        } else {
            // statistically unreachable overflow: compute sample directly
            const long long st = (long long)xs[it].x + (long long)xs[it].w * S_CNT;
            const long long rt = (long long)xs[it].y + (long long)xs[it].w * R_CNT;
            const long long p  = xs[it].z;
            float acc = 0.f;
            for (int k = 0; k < 64; ++k)
                acc += se[st * 64 + k] * pe[p * 128 + k]
                     + re[rt * 64 + k] * pe[p * 128 + 64 + k];
            out[i] = 1.0f / (1.0f + __expf(-acc));
        }
    }
}

// ---- pass 2: compute. R0's structure, in p-binned order; p via L1/L2. ----
// One block per bin; 16-lane groups; 2 samples per group per iteration.
__global__ __launch_bounds__(256, 8) void compute_kernel(
    const int* __restrict__ cursors, const int4* __restrict__ packed,
    const float* __restrict__ s_embeds, const float* __restrict__ r_embeds,
    const float* __restrict__ p_embeds, float* __restrict__ out)
{
    const int g = blockIdx.x;
    const int cnt = min(cursors[g], CAP);
    if (cnt == 0) return;

    const int gl = threadIdx.x >> 4;   // group 0..15
    const int l  = threadIdx.x & 15;   // lane in group
    const int4* pk = packed + (long long)g * CAP;
    const int last = cnt - 1;

    for (int sb = 0; sb < cnt; sb += 32) {
        const int jA = sb + gl * 2;
        const int jB = jA + 1;
        const int4 a = pk[min(jA, last)];   // broadcast within group (L1/L2, linear)
        const int4 b = pk[min(jB, last)];

        // 4 slow random gathers (s/r) + 4 p-window reads (L1/XCD-L2 hot)
        const float4 seA = *reinterpret_cast<const float4*>(s_embeds + (unsigned)a.x * 64u + l * 4);
        const float4 reA = *reinterpret_cast<const float4*>(r_embeds + (unsigned)a.y * 64u + l * 4);
        const float4 seB = *reinterpret_cast<const float4*>(s_embeds + (unsigned)b.x * 64u + l * 4);
        const float4 reB = *reinterpret_cast<const float4*>(r_embeds + (unsigned)b.y * 64u + l * 4);
        const float4 plA = *reinterpret_cast<const float4*>(p_embeds + (unsigned)a.z * 128u + l * 4);
        const float4 phA = *reinterpret_cast<const float4*>(p_embeds + (unsigned)a.z * 128u + 64u + l * 4);
        const float4 plB = *reinterpret_cast<const float4*>(p_embeds + (unsigned)b.z * 128u + l * 4);
        const float4 phB = *reinterpret_cast<const float4*>(p_embeds + (unsigned)b.z * 128u + 64u + l * 4);

        float accA = seA.x * plA.x + seA.y * plA.y + seA.z * plA.z + seA.w * plA.w
                   + reA.x * phA.x + reA.y * phA.y + reA.z * phA.z + reA.w * phA.w;
        float accB = seB.x * plB.x + seB.y * plB.y + seB.z * plB.z + seB.w * plB.w
                   + reB.x * phB.x + reB.y * phB.y + reB.z * phB.z + reB.w * phB.w;

        accA += __shfl_xor(accA, 1, 64);  accB += __shfl_xor(accB, 1, 64);
        accA += __shfl_xor(accA, 2, 64);  accB += __shfl_xor(accB, 2, 64);
        accA += __shfl_xor(accA, 4, 64);  accB += __shfl_xor(accB, 4, 64);
        accA += __shfl_xor(accA, 8, 64);  accB += __shfl_xor(accB, 8, 64);

        if (l == 0) {
            if (jA <= last) out[a.w] = 1.0f / (1.0f + __expf(-accA));
            if (jB <= last) out[b.w] = 1.0f / (1.0f + __expf(-accB));
        }
    }
}

// ---- fallback: direct kernel (only if workspace too small) ----
__global__ __launch_bounds__(256) void direct_kernel(
    const int* __restrict__ X,
    const float* __restrict__ s_embeds, const float* __restrict__ r_embeds,
    const float* __restrict__ p_embeds, float* __restrict__ out, int n) {
    const int g = threadIdx.x >> 4;
    const int l = threadIdx.x & 15;
    const int i = blockIdx.x * 16 + g;
    if (i >= n) return;
    const int4 xi = *reinterpret_cast<const int4*>(X + 4ll * i);
    const long long st = (long long)xi.x + (long long)xi.w * S_CNT;
    const long long rt = (long long)xi.y + (long long)xi.w * R_CNT;
    const long long p  = xi.z;
    const float4 se = *reinterpret_cast<const float4*>(s_embeds + st * 64 + l * 4);
    const float4 re = *reinterpret_cast<const float4*>(r_embeds + rt * 64 + l * 4);
    const float4 pl = *reinterpret_cast<const float4*>(p_embeds + p * 128 + l * 4);
    const float4 ph = *reinterpret_cast<const float4*>(p_embeds + p * 128 + 64 + l * 4);
    float acc = se.x * pl.x + se.y * pl.y + se.z * pl.z + se.w * pl.w
              + re.x * ph.x + re.y * ph.y + re.z * ph.z + re.w * ph.w;
    acc += __shfl_xor(acc, 1, 64);
    acc += __shfl_xor(acc, 2, 64);
    acc += __shfl_xor(acc, 4, 64);
    acc += __shfl_xor(acc, 8, 64);
    if (l == 0) out[i] = 1.0f / (1.0f + __expf(-acc));
}

extern "C" void kernel_launch(void* const* d_in, const int* in_sizes, int n_in,
                              void* d_out, int out_size, void* d_ws, size_t ws_size,
                              hipStream_t stream) {
    const int*   X        = (const int*)d_in[0];
    const float* s_embeds = (const float*)d_in[1];
    const float* r_embeds = (const float*)d_in[2];
    const float* p_embeds = (const float*)d_in[3];
    float* out = (float*)d_out;
    const int n = in_sizes[0] / 4;

    if (ws_size < WS_NEED) {
        direct_kernel<<<(n + 15) / 16, 256, 0, stream>>>(
            X, s_embeds, r_embeds, p_embeds, out, n);
        return;
    }

    int* cursors = (int*)d_ws;                                   // 2048 ints used
    int4* packed = reinterpret_cast<int4*>((char*)d_ws + PACKED_OFF_B);

    zero_kernel<<<2, 256, 0, stream>>>(reinterpret_cast<int4*>(cursors));
    bin_kernel<<<(n + 1023) / 1024, 256, 0, stream>>>(
        X, n, cursors, packed, s_embeds, r_embeds, p_embeds, out);
    compute_kernel<<<PG, 256, 0, stream>>>(
        cursors, packed, s_embeds, r_embeds, p_embeds, out);
}